// Round 2
// baseline (1439.850 us; speedup 1.0000x reference)
//
#include <hip/hip_runtime.h>
#include <hip/hip_bf16.h>

#define N_NODES 50000
#define N_EDGES 800000
#define NNZ_H   800000
#define M_HE    10000
#define F_IN    128
#define F_HID   64

// ---------------- degree / norm kernels ----------------

__global__ void k_count(const int* __restrict__ idx, int n, float* __restrict__ cnt) {
    int i = blockIdx.x * blockDim.x + threadIdx.x;
    if (i < n) atomicAdd(&cnt[idx[i]], 1.0f);
}

// GCN: dis[i] = rsqrt(cnt[i] + 1)   (self-loop adds 1, so always > 0)
__global__ void k_gcn_dis(float* __restrict__ d, int n) {
    int i = blockIdx.x * blockDim.x + threadIdx.x;
    if (i < n) d[i] = rsqrtf(d[i] + 1.0f);
}

// inv[i] = cnt>0 ? 1/cnt : 0
__global__ void k_inv(float* __restrict__ d, int n) {
    int i = blockIdx.x * blockDim.x + threadIdx.x;
    if (i < n) { float v = d[i]; d[i] = (v > 0.0f) ? (1.0f / v) : 0.0f; }
}

// ---------------- GEMM: (rows x K) @ (K x 64) -> fp32 ----------------
template<int K>
__global__ void k_gemm(const float* __restrict__ xin, const float* __restrict__ w,
                       float* __restrict__ out) {
    __shared__ float xs[K];
    int row = blockIdx.x;
    int f = threadIdx.x;  // 0..63
    for (int k = f; k < K; k += 64)
        xs[k] = xin[row * K + k];
    __syncthreads();
    float acc = 0.0f;
#pragma unroll 8
    for (int k = 0; k < K; ++k)
        acc += xs[k] * w[k * 64 + f];
    out[row * 64 + f] = acc;
}

// ---------------- GCN scatter: out[col] += dis[row]*dis[col] * xw[row] ----------------
__global__ void k_gcn_scatter(const int* __restrict__ row_idx, const int* __restrict__ col_idx,
                              const float* __restrict__ dis, const float* __restrict__ xw,
                              float* __restrict__ out) {
    long long t = (long long)blockIdx.x * blockDim.x + threadIdx.x;
    int e = (int)(t >> 6);
    int f = (int)(t & 63);
    if (e >= N_EDGES) return;
    int r = row_idx[e], c = col_idx[e];
    float norm = dis[r] * dis[c];
    atomicAdd(&out[c * 64 + f], norm * xw[r * 64 + f]);
}

// epilogue: out = agg + dis^2 * xw + b, optional ELU
template<bool ELU>
__global__ void k_gcn_epi(const float* __restrict__ agg, const float* __restrict__ xw,
                          const float* __restrict__ dis, const float* __restrict__ b,
                          float* __restrict__ out) {
    int t = blockIdx.x * blockDim.x + threadIdx.x;
    if (t >= N_NODES * 64) return;
    int i = t >> 6, f = t & 63;
    float d = dis[i];
    float v = agg[t] + d * d * xw[t] + b[f];
    if (ELU) v = (v > 0.0f) ? v : expm1f(v);
    out[t] = v;
}

// ---------------- Hypergraph scatters ----------------
__global__ void k_he_scatter(const int* __restrict__ node_idx, const int* __restrict__ he_idx,
                             const float* __restrict__ xw, float* __restrict__ ef) {
    long long t = (long long)blockIdx.x * blockDim.x + threadIdx.x;
    int e = (int)(t >> 6);
    int f = (int)(t & 63);
    if (e >= NNZ_H) return;
    atomicAdd(&ef[he_idx[e] * 64 + f], xw[node_idx[e] * 64 + f]);
}

__global__ void k_scale_rows(float* __restrict__ ef, const float* __restrict__ binv, int n) {
    int t = blockIdx.x * blockDim.x + threadIdx.x;
    if (t < n) ef[t] *= binv[t >> 6];
}

__global__ void k_node_scatter(const int* __restrict__ node_idx, const int* __restrict__ he_idx,
                               const float* __restrict__ ef, float* __restrict__ out) {
    long long t = (long long)blockIdx.x * blockDim.x + threadIdx.x;
    int e = (int)(t >> 6);
    int f = (int)(t & 63);
    if (e >= NNZ_H) return;
    atomicAdd(&out[node_idx[e] * 64 + f], ef[he_idx[e] * 64 + f]);
}

template<bool ELU>
__global__ void k_hyper_epi(const float* __restrict__ agg, const float* __restrict__ dinv,
                            const float* __restrict__ b, float* __restrict__ out) {
    int t = blockIdx.x * blockDim.x + threadIdx.x;
    if (t >= N_NODES * 64) return;
    int i = t >> 6, f = t & 63;
    float v = dinv[i] * agg[t] + b[f];
    if (ELU) v = (v > 0.0f) ? v : expm1f(v);
    out[t] = v;
}

// ---------------- fusion: z = a*x_s + (1-a)*x_d ----------------
__global__ void k_fuse(const float* __restrict__ xs, const float* __restrict__ xd,
                       const float* __restrict__ gate, float* __restrict__ z) {
    int t = blockIdx.x * blockDim.x + threadIdx.x;
    if (t >= N_NODES * 64) return;
    float g = gate[0];
    float a = 1.0f / (1.0f + expf(-g));
    z[t] = a * xs[t] + (1.0f - a) * xd[t];
}

extern "C" void kernel_launch(void* const* d_in, const int* in_sizes, int n_in,
                              void* d_out, int out_size, void* d_ws, size_t ws_size,
                              hipStream_t stream) {
    const float* x      = (const float*)d_in[0];
    const int*   ei     = (const int*)d_in[1];            // [2][E]
    const int*   hei    = (const int*)d_in[2];            // [2][NNZ]
    const float* gcn1_w = (const float*)d_in[3];
    const float* gcn1_b = (const float*)d_in[4];
    const float* gcn2_w = (const float*)d_in[5];
    const float* gcn2_b = (const float*)d_in[6];
    const float* hyp1_w = (const float*)d_in[7];
    const float* hyp1_b = (const float*)d_in[8];
    const float* hyp2_w = (const float*)d_in[9];
    const float* hyp2_b = (const float*)d_in[10];
    const float* gate   = (const float*)d_in[11];
    float* out = (float*)d_out;

    const int* e_row = ei;               // sources
    const int* e_col = ei + N_EDGES;     // targets
    const int* n_idx = hei;              // node ids
    const int* h_idx = hei + NNZ_H;      // hyperedge ids

    const size_t NV = (size_t)N_NODES * 64;
    float* z_out  = out;                 // [0,   NV)
    float* xs_out = out + NV;            // [NV, 2NV)  x_s accumulates here
    float* xd_out = out + 2 * NV;        // [2NV,3NV)  x_d accumulates here

    float* ws   = (float*)d_ws;
    float* A    = ws;                    // N*64  xw buffer
    float* AGG  = A + NV;                // N*64  h1 / hd1
    float* C    = AGG + NV;              // M*64  hyperedge features
    float* dis  = C + (size_t)M_HE * 64; // N
    float* dinv = dis + N_NODES;         // N
    float* binv = dinv + N_NODES;        // M

    const int BLK = 256;
    const int gN   = (N_NODES + BLK - 1) / BLK;
    const int gM   = (M_HE + BLK - 1) / BLK;
    const int gE   = (N_EDGES + BLK - 1) / BLK;
    const int gNNZ = (NNZ_H + BLK - 1) / BLK;
    const int gNV  = (int)((NV + BLK - 1) / BLK);               // 12500
    const int gMV  = (M_HE * 64 + BLK - 1) / BLK;               // 2500
    const int gEF  = (int)(((long long)N_EDGES * 64) / BLK);    // 200000
    const int gHF  = (int)(((long long)NNZ_H * 64) / BLK);      // 200000

    // --- degrees / norms ---
    hipMemsetAsync(dis,  0, N_NODES * sizeof(float), stream);
    hipMemsetAsync(dinv, 0, N_NODES * sizeof(float), stream);
    hipMemsetAsync(binv, 0, M_HE * sizeof(float), stream);
    k_count<<<gE, BLK, 0, stream>>>(e_col, N_EDGES, dis);
    k_count<<<gNNZ, BLK, 0, stream>>>(n_idx, NNZ_H, dinv);
    k_count<<<gNNZ, BLK, 0, stream>>>(h_idx, NNZ_H, binv);
    k_gcn_dis<<<gN, BLK, 0, stream>>>(dis, N_NODES);
    k_inv<<<gN, BLK, 0, stream>>>(dinv, N_NODES);
    k_inv<<<gM, BLK, 0, stream>>>(binv, M_HE);

    // --- GCN layer 1: A = x@w1 ; AGG = aggregate ; h1 = ELU(AGG + dis^2*A + b1) in AGG ---
    k_gemm<F_IN><<<N_NODES, 64, 0, stream>>>(x, gcn1_w, A);
    hipMemsetAsync(AGG, 0, NV * sizeof(float), stream);
    k_gcn_scatter<<<gEF, BLK, 0, stream>>>(e_row, e_col, dis, A, AGG);
    k_gcn_epi<true><<<gNV, BLK, 0, stream>>>(AGG, A, dis, gcn1_b, AGG);

    // --- GCN layer 2: A = h1@w2 ; x_s = agg + dis^2*A + b2 directly in out slot ---
    k_gemm<F_HID><<<N_NODES, 64, 0, stream>>>(AGG, gcn2_w, A);
    hipMemsetAsync(xs_out, 0, NV * sizeof(float), stream);
    k_gcn_scatter<<<gEF, BLK, 0, stream>>>(e_row, e_col, dis, A, xs_out);
    k_gcn_epi<false><<<gNV, BLK, 0, stream>>>(xs_out, A, dis, gcn2_b, xs_out);

    // --- Hyper layer 1: A = x@hw1 ; C = Binv*(H^T A) ; hd1 = ELU(Dinv*(H C) + b) in AGG ---
    k_gemm<F_IN><<<N_NODES, 64, 0, stream>>>(x, hyp1_w, A);
    hipMemsetAsync(C, 0, (size_t)M_HE * 64 * sizeof(float), stream);
    k_he_scatter<<<gHF, BLK, 0, stream>>>(n_idx, h_idx, A, C);
    k_scale_rows<<<gMV, BLK, 0, stream>>>(C, binv, M_HE * 64);
    hipMemsetAsync(AGG, 0, NV * sizeof(float), stream);
    k_node_scatter<<<gHF, BLK, 0, stream>>>(n_idx, h_idx, C, AGG);
    k_hyper_epi<true><<<gNV, BLK, 0, stream>>>(AGG, dinv, hyp1_b, AGG);

    // --- Hyper layer 2: A = hd1@hw2 ; x_d directly in out slot ---
    k_gemm<F_HID><<<N_NODES, 64, 0, stream>>>(AGG, hyp2_w, A);
    hipMemsetAsync(C, 0, (size_t)M_HE * 64 * sizeof(float), stream);
    k_he_scatter<<<gHF, BLK, 0, stream>>>(n_idx, h_idx, A, C);
    k_scale_rows<<<gMV, BLK, 0, stream>>>(C, binv, M_HE * 64);
    hipMemsetAsync(xd_out, 0, NV * sizeof(float), stream);
    k_node_scatter<<<gHF, BLK, 0, stream>>>(n_idx, h_idx, C, xd_out);
    k_hyper_epi<false><<<gNV, BLK, 0, stream>>>(xd_out, dinv, hyp2_b, xd_out);

    // --- fusion ---
    k_fuse<<<gNV, BLK, 0, stream>>>(xs_out, xd_out, gate, z_out);

    (void)in_sizes; (void)n_in; (void)out_size; (void)ws_size;
}

// Round 4
// 928.934 us; speedup vs baseline: 1.5500x; 1.5500x over previous
//
#include <hip/hip_runtime.h>
#include <hip/hip_bf16.h>

#define N_NODES 50000
#define N_EDGES 800000
#define NNZ_H   800000
#define M_HE    10000
#define F_IN    128
#define F_HID   64

// ---------------- counting ----------------
__global__ void k_count_int(const int* __restrict__ idx, int n, int* __restrict__ cnt) {
    int i = blockIdx.x * blockDim.x + threadIdx.x;
    if (i < n) atomicAdd(&cnt[idx[i]], 1);
}

// ---------------- exclusive scan (3-kernel, n <= ~64k) ----------------
__global__ void k_scan1(const int* __restrict__ in, int* __restrict__ out,
                        int* __restrict__ part, int n) {
    __shared__ int s[256];
    int i = blockIdx.x * 256 + threadIdx.x;
    int v = (i < n) ? in[i] : 0;
    s[threadIdx.x] = v;
    __syncthreads();
    for (int d = 1; d < 256; d <<= 1) {
        int t = (threadIdx.x >= d) ? s[threadIdx.x - d] : 0;
        __syncthreads();
        s[threadIdx.x] += t;
        __syncthreads();
    }
    if (i < n) out[i] = s[threadIdx.x] - v;          // exclusive
    if (threadIdx.x == 255) part[blockIdx.x] = s[255];
}
__global__ void k_scan2(int* __restrict__ part, int nb) {
    if (blockIdx.x == 0 && threadIdx.x == 0) {
        int run = 0;
        for (int i = 0; i < nb; ++i) { int t = part[i]; part[i] = run; run += t; }
    }
}
__global__ void k_scan3(int* __restrict__ out, const int* __restrict__ part, int n) {
    int i = blockIdx.x * 256 + threadIdx.x;
    if (i < n) out[i] += part[blockIdx.x];
}

// ---------------- position scatter (counting sort payload) ----------------
__global__ void k_sortscatter(const int* __restrict__ key, const int* __restrict__ val,
                              const int* __restrict__ off, int* __restrict__ cur,
                              int* __restrict__ outv, int n) {
    int i = blockIdx.x * blockDim.x + threadIdx.x;
    if (i < n) {
        int k = key[i];
        int p = off[k] + atomicAdd(&cur[k], 1);
        outv[p] = val[i];
    }
}

// dis[i] = rsqrt(deg + 1) from edge counts
__global__ void k_make_dis(const int* __restrict__ cnt, float* __restrict__ dis, int n) {
    int i = blockIdx.x * blockDim.x + threadIdx.x;
    if (i < n) dis[i] = rsqrtf((float)cnt[i] + 1.0f);
}

// ---------------- GEMM: (rows x K) @ (K x 64), w staged in LDS, 4 rows/block ----------------
template<int K>
__global__ void k_gemm(const float* __restrict__ xin, const float* __restrict__ w,
                       float* __restrict__ out) {
    __shared__ float wl[K * 64];
    __shared__ float xs[4][K];
    int tid = threadIdx.x;  // 256
    for (int i = tid; i < K * 64; i += 256) wl[i] = w[i];
    int r0 = blockIdx.x * 4;
    for (int i = tid; i < 4 * K; i += 256) {
        int rr = i / K, kk = i % K;
        xs[rr][kk] = xin[(size_t)(r0 + rr) * K + kk];
    }
    __syncthreads();
    int wv = tid >> 6, f = tid & 63;
    float acc = 0.0f;
#pragma unroll 8
    for (int k = 0; k < K; ++k)
        acc += xs[wv][k] * wl[k * 64 + f];
    out[(size_t)(r0 + wv) * 64 + f] = acc;
}

// ---------------- GCN gather: one wave per node, fused norm+selfloop+bias+ELU ----------------
template<bool ELU>
__global__ void k_gcn_gather(const int* __restrict__ off, const int* __restrict__ srcs,
                             const float* __restrict__ dis, const float* __restrict__ xw,
                             const float* __restrict__ b, float* __restrict__ out) {
    int wid = (blockIdx.x * blockDim.x + threadIdx.x) >> 6;
    int f = threadIdx.x & 63;
    if (wid >= N_NODES) return;
    int beg = off[wid], end = off[wid + 1];
    float acc = 0.0f;
    for (int e = beg; e < end; ++e) {
        int s = srcs[e];
        acc += dis[s] * xw[(size_t)s * 64 + f];
    }
    float di = dis[wid];
    float v = di * acc + di * di * xw[(size_t)wid * 64 + f] + b[f];
    if (ELU) v = (v > 0.0f) ? v : expm1f(v);
    out[(size_t)wid * 64 + f] = v;
}

// ---------------- hyperedge gather: one wave per hyperedge, fused Binv ----------------
__global__ void k_he_gather(const int* __restrict__ off, const int* __restrict__ nodes,
                            const float* __restrict__ xw, float* __restrict__ C) {
    int wid = (blockIdx.x * blockDim.x + threadIdx.x) >> 6;
    int f = threadIdx.x & 63;
    if (wid >= M_HE) return;
    int beg = off[wid], end = off[wid + 1];
    float acc = 0.0f;
    for (int e = beg; e < end; ++e)
        acc += xw[(size_t)nodes[e] * 64 + f];
    float binv = (end > beg) ? 1.0f / (float)(end - beg) : 0.0f;
    C[(size_t)wid * 64 + f] = binv * acc;
}

// ---------------- node gather from hyperedge feats: fused Dinv+bias+ELU ----------------
template<bool ELU>
__global__ void k_node_gather(const int* __restrict__ off, const int* __restrict__ hes,
                              const float* __restrict__ C, const float* __restrict__ b,
                              float* __restrict__ out) {
    int wid = (blockIdx.x * blockDim.x + threadIdx.x) >> 6;
    int f = threadIdx.x & 63;
    if (wid >= N_NODES) return;
    int beg = off[wid], end = off[wid + 1];
    float acc = 0.0f;
    for (int e = beg; e < end; ++e)
        acc += C[(size_t)hes[e] * 64 + f];
    float dinv = (end > beg) ? 1.0f / (float)(end - beg) : 0.0f;
    float v = dinv * acc + b[f];
    if (ELU) v = (v > 0.0f) ? v : expm1f(v);
    out[(size_t)wid * 64 + f] = v;
}

// ---------------- fusion ----------------
__global__ void k_fuse(const float* __restrict__ xs, const float* __restrict__ xd,
                       const float* __restrict__ gate, float* __restrict__ z) {
    int t = blockIdx.x * blockDim.x + threadIdx.x;
    if (t >= N_NODES * 64) return;
    float g = gate[0];
    float a = 1.0f / (1.0f + expf(-g));
    z[t] = a * xs[t] + (1.0f - a) * xd[t];
}

static inline void run_scan(const int* cnt, int* off, int* part, int n, hipStream_t stream) {
    int nb = (n + 255) / 256;
    k_scan1<<<nb, 256, 0, stream>>>(cnt, off, part, n);
    k_scan2<<<1, 1, 0, stream>>>(part, nb);
    k_scan3<<<nb, 256, 0, stream>>>(off, part, n);
}

extern "C" void kernel_launch(void* const* d_in, const int* in_sizes, int n_in,
                              void* d_out, int out_size, void* d_ws, size_t ws_size,
                              hipStream_t stream) {
    const float* x      = (const float*)d_in[0];
    const int*   ei     = (const int*)d_in[1];            // [2][E]
    const int*   hei    = (const int*)d_in[2];            // [2][NNZ]
    const float* gcn1_w = (const float*)d_in[3];
    const float* gcn1_b = (const float*)d_in[4];
    const float* gcn2_w = (const float*)d_in[5];
    const float* gcn2_b = (const float*)d_in[6];
    const float* hyp1_w = (const float*)d_in[7];
    const float* hyp1_b = (const float*)d_in[8];
    const float* hyp2_w = (const float*)d_in[9];
    const float* hyp2_b = (const float*)d_in[10];
    const float* gate   = (const float*)d_in[11];
    float* out = (float*)d_out;

    const int* e_row = ei;               // sources
    const int* e_col = ei + N_EDGES;     // targets
    const int* n_idx = hei;              // node ids
    const int* h_idx = hei + NNZ_H;      // hyperedge ids

    const size_t NV = (size_t)N_NODES * 64;
    float* z_out  = out;
    float* xs_out = out + NV;
    float* xd_out = out + 2 * NV;

    // ---- workspace layout (about 39.5 MB) ----
    float* A    = (float*)d_ws;          // N*64
    float* AGG  = A + NV;                // N*64
    float* C    = AGG + NV;              // M*64
    float* dis  = C + (size_t)M_HE * 64; // N
    int* srtE = (int*)(dis + N_NODES);   // E: src sorted by dst
    int* srtH = srtE + N_EDGES;          // NNZ: node_idx sorted by he
    int* srtN = srtH + NNZ_H;            // NNZ: he_idx sorted by node
    int* offE = srtN + NNZ_H;            // N+1
    int* offH = offE + (N_NODES + 1);    // M+1
    int* offN = offH + (M_HE + 1);       // N+1
    // contiguous zero block below:
    int* cntE = offN + (N_NODES + 1);    // N+1
    int* cntH = cntE + (N_NODES + 1);    // M+1
    int* cntN = cntH + (M_HE + 1);       // N+1
    int* curE = cntN + (N_NODES + 1);    // N
    int* curH = curE + N_NODES;          // M
    int* curN = curH + M_HE;             // N
    int* part = curN + N_NODES;          // 256
    const size_t zero_ints = (size_t)(N_NODES + 1) * 2 + (M_HE + 1) + N_NODES * 2 + M_HE;

    const int BLK = 256;
    const int gE   = (N_EDGES + BLK - 1) / BLK;
    const int gNNZ = (NNZ_H + BLK - 1) / BLK;
    const int gN   = (N_NODES + BLK - 1) / BLK;
    const int gNV  = (int)((NV + BLK - 1) / BLK);
    const int gWN  = N_NODES / 4;        // wave-per-node blocks
    const int gWM  = M_HE / 4;           // wave-per-hyperedge blocks

    // ---- counting sort: counts (= degrees), offsets, payload scatter ----
    hipMemsetAsync(cntE, 0, zero_ints * sizeof(int), stream);
    k_count_int<<<gE,   BLK, 0, stream>>>(e_col, N_EDGES, cntE);
    k_count_int<<<gNNZ, BLK, 0, stream>>>(h_idx, NNZ_H,  cntH);
    k_count_int<<<gNNZ, BLK, 0, stream>>>(n_idx, NNZ_H,  cntN);
    run_scan(cntE, offE, part, N_NODES + 1, stream);
    run_scan(cntH, offH, part, M_HE + 1,   stream);
    run_scan(cntN, offN, part, N_NODES + 1, stream);
    k_make_dis<<<gN, BLK, 0, stream>>>(cntE, dis, N_NODES);
    k_sortscatter<<<gE,   BLK, 0, stream>>>(e_col, e_row, offE, curE, srtE, N_EDGES);
    k_sortscatter<<<gNNZ, BLK, 0, stream>>>(h_idx, n_idx, offH, curH, srtH, NNZ_H);
    k_sortscatter<<<gNNZ, BLK, 0, stream>>>(n_idx, h_idx, offN, curN, srtN, NNZ_H);

    // ---- GCN layer 1: A = x@w1 ; AGG = ELU(gather + selfloop + b1) ----
    k_gemm<F_IN><<<gWN, BLK, 0, stream>>>(x, gcn1_w, A);
    k_gcn_gather<true><<<gWN, BLK, 0, stream>>>(offE, srtE, dis, A, gcn1_b, AGG);

    // ---- GCN layer 2: A = AGG@w2 ; x_s ----
    k_gemm<F_HID><<<gWN, BLK, 0, stream>>>(AGG, gcn2_w, A);
    k_gcn_gather<false><<<gWN, BLK, 0, stream>>>(offE, srtE, dis, A, gcn2_b, xs_out);

    // ---- Hyper layer 1: A = x@hw1 ; C = Binv*(H^T A) ; AGG = ELU(Dinv*(H C) + b1) ----
    k_gemm<F_IN><<<gWN, BLK, 0, stream>>>(x, hyp1_w, A);
    k_he_gather<<<gWM, BLK, 0, stream>>>(offH, srtH, A, C);
    k_node_gather<true><<<gWN, BLK, 0, stream>>>(offN, srtN, C, hyp1_b, AGG);

    // ---- Hyper layer 2 ----
    k_gemm<F_HID><<<gWN, BLK, 0, stream>>>(AGG, hyp2_w, A);
    k_he_gather<<<gWM, BLK, 0, stream>>>(offH, srtH, A, C);
    k_node_gather<false><<<gWN, BLK, 0, stream>>>(offN, srtN, C, hyp2_b, xd_out);

    // ---- fusion ----
    k_fuse<<<gNV, BLK, 0, stream>>>(xs_out, xd_out, gate, z_out);

    (void)in_sizes; (void)n_in; (void)out_size; (void)ws_size;
}

// Round 5
// 723.148 us; speedup vs baseline: 1.9911x; 1.2846x over previous
//
#include <hip/hip_runtime.h>
#include <hip/hip_bf16.h>

#define N_NODES 50000
#define N_EDGES 800000
#define NNZ_H   800000
#define M_HE    10000
#define F_IN    128
#define F_HID   64

// ---------------- fused counting (all three CSR builds) ----------------
__global__ void k_count_all(const int* __restrict__ e_col, const int* __restrict__ h_idx,
                            const int* __restrict__ n_idx,
                            int* __restrict__ cntE, int* __restrict__ cntH, int* __restrict__ cntN) {
    int i = blockIdx.x * blockDim.x + threadIdx.x;
    if (i < N_EDGES) atomicAdd(&cntE[e_col[i]], 1);
    if (i < NNZ_H) {
        atomicAdd(&cntH[h_idx[i]], 1);
        atomicAdd(&cntN[n_idx[i]], 1);
    }
}

// ---------------- single-kernel exclusive scans (1024-thread block scan) ----------------
__device__ void scan_block(const int* __restrict__ in, int* __restrict__ out, int n) {
    __shared__ int s[1024];
    int t = threadIdx.x;
    int chunk = (n + 1023) >> 10;
    int b = t * chunk;
    int e = min(b + chunk, n);
    int sum = 0;
    for (int i = b; i < e; ++i) sum += in[i];
    s[t] = sum;
    __syncthreads();
    for (int d = 1; d < 1024; d <<= 1) {
        int v = (t >= d) ? s[t - d] : 0;
        __syncthreads();
        s[t] += v;
        __syncthreads();
    }
    int run = (t > 0) ? s[t - 1] : 0;
    for (int i = b; i < e; ++i) { int v = in[i]; out[i] = run; run += v; }
}
__global__ void k_scan_all(const int* __restrict__ cntE, int* __restrict__ offE,
                           const int* __restrict__ cntH, int* __restrict__ offH,
                           const int* __restrict__ cntN, int* __restrict__ offN) {
    if (blockIdx.x == 0)      scan_block(cntE, offE, N_NODES + 1);
    else if (blockIdx.x == 1) scan_block(cntH, offH, M_HE + 1);
    else                      scan_block(cntN, offN, N_NODES + 1);
}

// ---------------- fused position scatter (counting-sort payloads) ----------------
__global__ void k_scatter_all(const int* __restrict__ e_row, const int* __restrict__ e_col,
                              const int* __restrict__ n_idx, const int* __restrict__ h_idx,
                              const int* __restrict__ offE, int* __restrict__ curE, int* __restrict__ srtE,
                              const int* __restrict__ offH, int* __restrict__ curH, int* __restrict__ srtH,
                              const int* __restrict__ offN, int* __restrict__ curN, int* __restrict__ srtN) {
    int i = blockIdx.x * blockDim.x + threadIdx.x;
    if (i < N_EDGES) {
        int k = e_col[i];
        srtE[offE[k] + atomicAdd(&curE[k], 1)] = e_row[i];
    }
    if (i < NNZ_H) {
        int k = h_idx[i];
        srtH[offH[k] + atomicAdd(&curH[k], 1)] = n_idx[i];
        int k2 = n_idx[i];
        srtN[offN[k2] + atomicAdd(&curN[k2], 1)] = h_idx[i];
    }
}

// ---------------- GEMM: (rows x K) @ (K x 64), w in LDS, 4 rows/block ----------------
// SCALE: multiply row result by dis[row] = rsqrt(deg+1) (GCN pre-scaling)
template<int K, bool SCALE>
__global__ void k_gemm(const float* __restrict__ xin, const float* __restrict__ w,
                       const int* __restrict__ cntE, float* __restrict__ out) {
    __shared__ float wl[K * 64];
    __shared__ float xs[4][K];
    int tid = threadIdx.x;  // 256
    for (int i = tid; i < K * 64; i += 256) wl[i] = w[i];
    int r0 = blockIdx.x * 4;
    for (int i = tid; i < 4 * K; i += 256) {
        int rr = i / K, kk = i % K;
        xs[rr][kk] = xin[(size_t)(r0 + rr) * K + kk];
    }
    __syncthreads();
    int wv = tid >> 6, f = tid & 63;
    float acc = 0.0f;
#pragma unroll 8
    for (int k = 0; k < K; ++k)
        acc += xs[wv][k] * wl[k * 64 + f];
    if (SCALE) {
        float di = rsqrtf((float)cntE[r0 + wv] + 1.0f);
        acc *= di;
    }
    out[(size_t)(r0 + wv) * 64 + f] = acc;
}

// ---------------- GCN gather on pre-scaled A': out = di*(sum + A'[i]) + b ----------------
template<bool ELU>
__global__ void k_gcn_gather(const int* __restrict__ off, const int* __restrict__ srcs,
                             const float* __restrict__ xw, const float* __restrict__ b,
                             float* __restrict__ out) {
    int wid = (blockIdx.x * blockDim.x + threadIdx.x) >> 6;
    int f = threadIdx.x & 63;
    if (wid >= N_NODES) return;
    int beg = off[wid], end = off[wid + 1];
    float a0 = 0, a1 = 0, a2 = 0, a3 = 0;
    int e = beg;
    for (; e + 4 <= end; e += 4) {
        int s0 = srcs[e], s1 = srcs[e + 1], s2 = srcs[e + 2], s3 = srcs[e + 3];
        a0 += xw[(size_t)s0 * 64 + f];
        a1 += xw[(size_t)s1 * 64 + f];
        a2 += xw[(size_t)s2 * 64 + f];
        a3 += xw[(size_t)s3 * 64 + f];
    }
    for (; e < end; ++e) a0 += xw[(size_t)srcs[e] * 64 + f];
    float acc = (a0 + a1) + (a2 + a3);
    float di = rsqrtf((float)(end - beg) + 1.0f);
    float v = di * (acc + xw[(size_t)wid * 64 + f]) + b[f];
    if (ELU) v = (v > 0.0f) ? v : expm1f(v);
    out[(size_t)wid * 64 + f] = v;
}

// ---------------- hyperedge gather: one BLOCK per hyperedge, 4-wave split + unroll ----------------
__global__ void k_he_gather(const int* __restrict__ off, const int* __restrict__ nodes,
                            const float* __restrict__ xw, float* __restrict__ C) {
    __shared__ float red[4][64];
    int he = blockIdx.x;
    int wv = threadIdx.x >> 6, f = threadIdx.x & 63;
    int beg = off[he], end = off[he + 1];
    int cnt = end - beg;
    int per = (cnt + 3) >> 2;
    int b0 = beg + wv * per;
    int e0 = min(b0 + per, end);
    float a0 = 0, a1 = 0, a2 = 0, a3 = 0;
    int e = b0;
    for (; e + 4 <= e0; e += 4) {
        int s0 = nodes[e], s1 = nodes[e + 1], s2 = nodes[e + 2], s3 = nodes[e + 3];
        a0 += xw[(size_t)s0 * 64 + f];
        a1 += xw[(size_t)s1 * 64 + f];
        a2 += xw[(size_t)s2 * 64 + f];
        a3 += xw[(size_t)s3 * 64 + f];
    }
    for (; e < e0; ++e) a0 += xw[(size_t)nodes[e] * 64 + f];
    red[wv][f] = (a0 + a1) + (a2 + a3);
    __syncthreads();
    if (wv == 0) {
        float tot = (red[0][f] + red[1][f]) + (red[2][f] + red[3][f]);
        float binv = (cnt > 0) ? 1.0f / (float)cnt : 0.0f;
        C[(size_t)he * 64 + f] = binv * tot;
    }
}

// ---------------- node gather from hyperedge feats: fused Dinv+bias+ELU ----------------
template<bool ELU>
__global__ void k_node_gather(const int* __restrict__ off, const int* __restrict__ hes,
                              const float* __restrict__ C, const float* __restrict__ b,
                              float* __restrict__ out) {
    int wid = (blockIdx.x * blockDim.x + threadIdx.x) >> 6;
    int f = threadIdx.x & 63;
    if (wid >= N_NODES) return;
    int beg = off[wid], end = off[wid + 1];
    float a0 = 0, a1 = 0, a2 = 0, a3 = 0;
    int e = beg;
    for (; e + 4 <= end; e += 4) {
        int s0 = hes[e], s1 = hes[e + 1], s2 = hes[e + 2], s3 = hes[e + 3];
        a0 += C[(size_t)s0 * 64 + f];
        a1 += C[(size_t)s1 * 64 + f];
        a2 += C[(size_t)s2 * 64 + f];
        a3 += C[(size_t)s3 * 64 + f];
    }
    for (; e < end; ++e) a0 += C[(size_t)hes[e] * 64 + f];
    float acc = (a0 + a1) + (a2 + a3);
    float dinv = (end > beg) ? 1.0f / (float)(end - beg) : 0.0f;
    float v = dinv * acc + b[f];
    if (ELU) v = (v > 0.0f) ? v : expm1f(v);
    out[(size_t)wid * 64 + f] = v;
}

// ---------------- fusion (float4) ----------------
__global__ void k_fuse(const float4* __restrict__ xs, const float4* __restrict__ xd,
                       const float* __restrict__ gate, float4* __restrict__ z) {
    int t = blockIdx.x * blockDim.x + threadIdx.x;
    if (t >= N_NODES * 16) return;
    float a = 1.0f / (1.0f + expf(-gate[0]));
    float4 s = xs[t], d = xd[t];
    float4 o;
    o.x = a * s.x + (1.0f - a) * d.x;
    o.y = a * s.y + (1.0f - a) * d.y;
    o.z = a * s.z + (1.0f - a) * d.z;
    o.w = a * s.w + (1.0f - a) * d.w;
    z[t] = o;
}

extern "C" void kernel_launch(void* const* d_in, const int* in_sizes, int n_in,
                              void* d_out, int out_size, void* d_ws, size_t ws_size,
                              hipStream_t stream) {
    const float* x      = (const float*)d_in[0];
    const int*   ei     = (const int*)d_in[1];
    const int*   hei    = (const int*)d_in[2];
    const float* gcn1_w = (const float*)d_in[3];
    const float* gcn1_b = (const float*)d_in[4];
    const float* gcn2_w = (const float*)d_in[5];
    const float* gcn2_b = (const float*)d_in[6];
    const float* hyp1_w = (const float*)d_in[7];
    const float* hyp1_b = (const float*)d_in[8];
    const float* hyp2_w = (const float*)d_in[9];
    const float* hyp2_b = (const float*)d_in[10];
    const float* gate   = (const float*)d_in[11];
    float* out = (float*)d_out;

    const int* e_row = ei;               // sources
    const int* e_col = ei + N_EDGES;     // targets
    const int* n_idx = hei;              // node ids
    const int* h_idx = hei + NNZ_H;      // hyperedge ids

    const size_t NV = (size_t)N_NODES * 64;
    float* z_out  = out;
    float* xs_out = out + NV;
    float* xd_out = out + 2 * NV;

    // ---- workspace layout ----
    float* A    = (float*)d_ws;          // N*64
    float* AGG  = A + NV;                // N*64
    float* C    = AGG + NV;              // M*64
    int* srtE = (int*)(C + (size_t)M_HE * 64);  // E
    int* srtH = srtE + N_EDGES;          // NNZ
    int* srtN = srtH + NNZ_H;            // NNZ
    int* offE = srtN + NNZ_H;            // N+1
    int* offH = offE + (N_NODES + 1);    // M+1
    int* offN = offH + (M_HE + 1);       // N+1
    // contiguous zero block:
    int* cntE = offN + (N_NODES + 1);    // N+1
    int* cntH = cntE + (N_NODES + 1);    // M+1
    int* cntN = cntH + (M_HE + 1);       // N+1
    int* curE = cntN + (N_NODES + 1);    // N
    int* curH = curE + N_NODES;          // M
    int* curN = curH + M_HE;             // N
    const size_t zero_ints = (size_t)(N_NODES + 1) * 2 + (M_HE + 1)
                           + (size_t)N_NODES * 2 + M_HE;

    const int BLK = 256;
    const int gBig = (N_EDGES + BLK - 1) / BLK;       // covers E == NNZ
    const int gWN  = N_NODES / 4;                      // 12500 (4 rows/block)
    const int gF4  = (N_NODES * 16 + BLK - 1) / BLK;

    // ---- CSR build ----
    hipMemsetAsync(cntE, 0, zero_ints * sizeof(int), stream);
    k_count_all<<<gBig, BLK, 0, stream>>>(e_col, h_idx, n_idx, cntE, cntH, cntN);
    k_scan_all<<<3, 1024, 0, stream>>>(cntE, offE, cntH, offH, cntN, offN);
    k_scatter_all<<<gBig, BLK, 0, stream>>>(e_row, e_col, n_idx, h_idx,
                                            offE, curE, srtE,
                                            offH, curH, srtH,
                                            offN, curN, srtN);

    // ---- GCN layer 1: A = dis.*(x@w1) ; AGG = ELU(di*(gather+self) + b1) ----
    k_gemm<F_IN, true><<<gWN, BLK, 0, stream>>>(x, gcn1_w, cntE, A);
    k_gcn_gather<true><<<gWN, BLK, 0, stream>>>(offE, srtE, A, gcn1_b, AGG);

    // ---- GCN layer 2 ----
    k_gemm<F_HID, true><<<gWN, BLK, 0, stream>>>(AGG, gcn2_w, cntE, A);
    k_gcn_gather<false><<<gWN, BLK, 0, stream>>>(offE, srtE, A, gcn2_b, xs_out);

    // ---- Hyper layer 1 ----
    k_gemm<F_IN, false><<<gWN, BLK, 0, stream>>>(x, hyp1_w, nullptr, A);
    k_he_gather<<<M_HE, BLK, 0, stream>>>(offH, srtH, A, C);
    k_node_gather<true><<<gWN, BLK, 0, stream>>>(offN, srtN, C, hyp1_b, AGG);

    // ---- Hyper layer 2 ----
    k_gemm<F_HID, false><<<gWN, BLK, 0, stream>>>(AGG, hyp2_w, nullptr, A);
    k_he_gather<<<M_HE, BLK, 0, stream>>>(offH, srtH, A, C);
    k_node_gather<false><<<gWN, BLK, 0, stream>>>(offN, srtN, C, hyp2_b, xd_out);

    // ---- fusion ----
    k_fuse<<<gF4, BLK, 0, stream>>>((const float4*)xs_out, (const float4*)xd_out, gate, (float4*)z_out);

    (void)in_sizes; (void)n_in; (void)out_size; (void)ws_size;
}